// Round 9
// baseline (183.847 us; speedup 1.0000x reference)
//
#include <hip/hip_runtime.h>
#include <hip/hip_bf16.h>
#include <math.h>

#define D 40
#define DIN 128
#define S 2048
#define B 8
#define NROWS (B*S)   // 16384
#define DP 64         // padded depth for Q/K bf16 rows
#define DVP 64        // padded depth (rows) for transposed V
#define XSTR 48       // xb / po row stride (ushorts)
#define NQT (S/128)   // q-tiles per batch (16)

typedef __bf16 bf16x8 __attribute__((ext_vector_type(8)));
typedef float f32x4 __attribute__((ext_vector_type(4)));
typedef float f32x16 __attribute__((ext_vector_type(16)));

static __device__ __forceinline__ unsigned short f2bf(float f) {
    unsigned u = __builtin_bit_cast(unsigned, f);
    u += 0x7fff + ((u >> 16) & 1);   // RNE
    return (unsigned short)(u >> 16);
}
static __device__ __forceinline__ float bf2f(unsigned short h) {
    return __builtin_bit_cast(float, (unsigned)h << 16);
}
static __device__ __forceinline__ bf16x8 ldfrag(const unsigned short* p) {
    return __builtin_bit_cast(bf16x8, *(const uint4*)p);
}
static __device__ __forceinline__ unsigned cvtpk(float lo, float hi) {
    unsigned r;
    asm("v_cvt_pk_bf16_f32 %0, %1, %2" : "=v"(r) : "v"(lo), "v"(hi));
    return r;
}
static __device__ __forceinline__ void plswap(unsigned &a, unsigned &b) {
    asm("v_permlane32_swap_b32 %0, %1" : "+v"(a), "+v"(b));
}

// ---------------- Kernel 0: weight prep + bias table + counter zero ----------------
__global__ __launch_bounds__(256) void k0_prep(
    const float* __restrict__ Wa, const float* __restrict__ ba, const float* __restrict__ ln1,
    const float* __restrict__ Wq, const float* __restrict__ Wk, const float* __restrict__ Wv,
    const float* __restrict__ Wo, const float* __restrict__ ln2,
    const float* __restrict__ wi, const float* __restrict__ wo,
    const float* __restrict__ rel_bias,
    unsigned short* __restrict__ waT, unsigned short* __restrict__ wqT,
    unsigned short* __restrict__ wkT, unsigned short* __restrict__ wvT,
    unsigned short* __restrict__ woT, unsigned short* __restrict__ wiT,
    unsigned short* __restrict__ wo2T, float* __restrict__ btab,
    int* __restrict__ cnt)
{
    int i = blockIdx.x * 256 + threadIdx.x;
    if (i < 64*144) {
        int col = i / 144, k = i - col*144;
        float v = 0.f;
        if (col < D) {
            if (k < DIN) v = Wa[k*D + col];
            else if (k == DIN) v = ba[col];
        }
        waT[i] = f2bf(v);
    }
    if (i < 64*48) {
        int col = i / 48, d = i - col*48;
        bool ok = (col < D && d < D);
        float s1 = ok ? ln1[d] : 0.f;
        float s2 = ok ? ln2[d] : 0.f;
        wqT[i]  = f2bf(ok ? Wq[d*D + col] * s1 : 0.f);
        wkT[i]  = f2bf(ok ? Wk[d*D + col] * s1 : 0.f);
        wvT[i]  = f2bf(ok ? Wv[d*D + col] * s1 : 0.f);
        woT[i]  = f2bf(ok ? Wo[d*D + col]      : 0.f);
        wiT[i]  = f2bf(ok ? wi[d*D + col] * s2 : 0.f);
        wo2T[i] = f2bf(ok ? wo[d*D + col]      : 0.f);
    }
    if (i < 2*S - 1) {
        int rel = i - (S - 1);          // rel = k - q
        int bucket = (rel > 0) ? 16 : 0;
        int ar = rel < 0 ? -rel : rel;
        int add;
        if (ar < 8) {
            add = ar;
        } else {
            float tt = logf((float)ar * 0.125f) / logf(16.0f) * 8.0f;
            int lg = 8 + (int)tt;
            add = lg < 15 ? lg : 15;
        }
        btab[i] = rel_bias[bucket + add];
    }
    if (i < B*NQT) cnt[i] = 0;   // split-K arrival counters (re-zeroed every launch)
}

// C-layout -> row-major bf16 frags (validated in k1/k3):
static __device__ __forceinline__ void repack_cl(
    const f32x16& t0, const f32x16& t1, uint4& u0, uint4& u1, uint4& u2)
{
    unsigned a0=cvtpk(t0[0],t0[1]),  a1=cvtpk(t0[2],t0[3]),
             a2=cvtpk(t0[4],t0[5]),  a3=cvtpk(t0[6],t0[7]);
    plswap(a0,a2); plswap(a1,a3);
    unsigned b0=cvtpk(t0[8],t0[9]),  b1=cvtpk(t0[10],t0[11]),
             b2=cvtpk(t0[12],t0[13]),b3=cvtpk(t0[14],t0[15]);
    plswap(b0,b2); plswap(b1,b3);
    unsigned c0=cvtpk(t1[0],t1[1]),  c1=cvtpk(t1[2],t1[3]),
             c2=cvtpk(t1[4],t1[5]),  c3=cvtpk(t1[6],t1[7]);
    plswap(c0,c2); plswap(c1,c3);
    u0 = (uint4){a0,a1,a2,a3}; u1 = (uint4){b0,b1,b2,b3}; u2 = (uint4){c0,c1,c2,c3};
}

// ---------------- Kernel 1: adapter + rmsnorm + QKV, all-MFMA ----------------
__global__ __launch_bounds__(64) void k1_adapter_qkv(
    const float* __restrict__ embs,
    const unsigned short* __restrict__ waT, const unsigned short* __restrict__ wqT,
    const unsigned short* __restrict__ wkT, const unsigned short* __restrict__ wvT,
    unsigned short* __restrict__ xb, unsigned short* __restrict__ qb,
    unsigned short* __restrict__ kbq, unsigned short* __restrict__ vT)
{
    const int l  = threadIdx.x;
    const int lr = l & 31, hi = l >> 5;
    const int row = blockIdx.x * 32 + lr;

    const float* erow = embs + (size_t)row * DIN;
    bf16x8 eb[9];
    #pragma unroll
    for (int kk = 0; kk < 8; ++kk) {
        float4 f0 = *(const float4*)(erow + kk*16 + hi*8);
        float4 f1 = *(const float4*)(erow + kk*16 + hi*8 + 4);
        uint4 u = { cvtpk(f0.x, f0.y), cvtpk(f0.z, f0.w),
                    cvtpk(f1.x, f1.y), cvtpk(f1.z, f1.w) };
        eb[kk] = __builtin_bit_cast(bf16x8, u);
    }
    {
        uint4 u = { hi == 0 ? 0x3f80u : 0u, 0u, 0u, 0u };
        eb[8] = __builtin_bit_cast(bf16x8, u);
    }

    f32x16 x0 = {0,0,0,0,0,0,0,0,0,0,0,0,0,0,0,0};
    f32x16 x1 = {0,0,0,0,0,0,0,0,0,0,0,0,0,0,0,0};
    #pragma unroll
    for (int kk = 0; kk < 9; ++kk) {
        bf16x8 a0 = ldfrag(waT + lr*144      + kk*16 + hi*8);
        bf16x8 a1 = ldfrag(waT + (32+lr)*144 + kk*16 + hi*8);
        x0 = __builtin_amdgcn_mfma_f32_32x32x16_bf16(a0, eb[kk], x0, 0,0,0);
        x1 = __builtin_amdgcn_mfma_f32_32x32x16_bf16(a1, eb[kk], x1, 0,0,0);
    }

    float ss = 0.f;
    #pragma unroll
    for (int r = 0; r < 16; ++r) {
        x0[r] = fmaxf(x0[r], 0.f);
        x1[r] = fmaxf(x1[r], 0.f);
        ss += x0[r]*x0[r] + x1[r]*x1[r];
    }
    ss += __shfl_xor(ss, 32);
    const float inv = rsqrtf(ss * (1.0f/D) + 1e-6f);

    {
        uint4 u0,u1,u2; repack_cl(x0, x1, u0, u1, u2);
        unsigned short* p = xb + (size_t)row*XSTR;
        *(uint4*)(p + hi*8)      = u0;
        *(uint4*)(p + 16 + hi*8) = u1;
        *(uint4*)(p + 32 + hi*8) = u2;
    }

    #pragma unroll
    for (int r = 0; r < 16; ++r) { x0[r] *= inv; x1[r] *= inv; }
    uint4 h0,h1,h2; repack_cl(x0, x1, h0, h1, h2);
    bf16x8 hb[3] = { __builtin_bit_cast(bf16x8, h0),
                     __builtin_bit_cast(bf16x8, h1),
                     __builtin_bit_cast(bf16x8, h2) };

    f32x16 qa0={0,0,0,0,0,0,0,0,0,0,0,0,0,0,0,0}, qa1={0,0,0,0,0,0,0,0,0,0,0,0,0,0,0,0};
    f32x16 ka0={0,0,0,0,0,0,0,0,0,0,0,0,0,0,0,0}, ka1={0,0,0,0,0,0,0,0,0,0,0,0,0,0,0,0};
    f32x16 va0={0,0,0,0,0,0,0,0,0,0,0,0,0,0,0,0}, va1={0,0,0,0,0,0,0,0,0,0,0,0,0,0,0,0};
    #pragma unroll
    for (int t = 0; t < 3; ++t) {
        bf16x8 h = hb[t];
        qa0 = __builtin_amdgcn_mfma_f32_32x32x16_bf16(ldfrag(wqT + lr*48      + t*16 + hi*8), h, qa0, 0,0,0);
        qa1 = __builtin_amdgcn_mfma_f32_32x32x16_bf16(ldfrag(wqT + (32+lr)*48 + t*16 + hi*8), h, qa1, 0,0,0);
        ka0 = __builtin_amdgcn_mfma_f32_32x32x16_bf16(ldfrag(wkT + lr*48      + t*16 + hi*8), h, ka0, 0,0,0);
        ka1 = __builtin_amdgcn_mfma_f32_32x32x16_bf16(ldfrag(wkT + (32+lr)*48 + t*16 + hi*8), h, ka1, 0,0,0);
        va0 = __builtin_amdgcn_mfma_f32_32x32x16_bf16(ldfrag(wvT + lr*48      + t*16 + hi*8), h, va0, 0,0,0);
        va1 = __builtin_amdgcn_mfma_f32_32x32x16_bf16(ldfrag(wvT + (32+lr)*48 + t*16 + hi*8), h, va1, 0,0,0);
    }

    {
        uint4 u0,u1,u2; repack_cl(qa0, qa1, u0, u1, u2);
        unsigned short* p = qb + (size_t)row*DP;
        *(uint4*)(p + hi*8) = u0; *(uint4*)(p + 16 + hi*8) = u1; *(uint4*)(p + 32 + hi*8) = u2;
    }
    {
        uint4 u0,u1,u2; repack_cl(ka0, ka1, u0, u1, u2);
        unsigned short* p = kbq + (size_t)row*DP;
        *(uint4*)(p + hi*8) = u0; *(uint4*)(p + 16 + hi*8) = u1; *(uint4*)(p + 32 + hi*8) = u2;
    }
    #pragma unroll
    for (int r = 0; r < 16; ++r) {
        int col = (r&3) + 8*(r>>2) + 4*hi;
        vT[(size_t)col*NROWS + row] = f2bf(va0[r]);
        if (r < 4) vT[(size_t)(32 + (r&3) + 4*hi)*NROWS + row] = f2bf(va1[r]);
    }
    #pragma unroll
    for (int c = 0; c < 12; ++c) {
        vT[(size_t)(D + 2*c + hi)*NROWS + row] = 0;
    }
}

// ---------------- Kernel 3: flash attention + split-K fixup (O-proj+FF fused) ----------------
__global__ __launch_bounds__(256) void k3_attn_fused(
    const unsigned short* __restrict__ qb, const unsigned short* __restrict__ kb,
    const unsigned short* __restrict__ vT, const float* __restrict__ btab,
    const unsigned short* __restrict__ xb,
    const unsigned short* __restrict__ woT, const unsigned short* __restrict__ wiT,
    const unsigned short* __restrict__ wo2T, const float* __restrict__ lnf,
    unsigned short* __restrict__ pob, float* __restrict__ pl,
    int* __restrict__ cnt, float* __restrict__ out,
    int klen, int nsplit)
{
    __shared__ float sbtw[2176 + 16];
    __shared__ int sdone;

    const int q0blk = blockIdx.x * 128;
    const int kt0   = blockIdx.z * klen;
    const int woff  = (S-1) + kt0 - q0blk - 127;

    int tid = threadIdx.x;
    for (int i = tid; i < klen + 128; i += 256) {
        int g = woff + i;
        sbtw[i] = btab[g < 0 ? 0 : (g > 4094 ? 4094 : g)];
    }
    __syncthreads();

    const int w  = tid >> 6, l = tid & 63;
    const int lr = l & 31,  hi = l >> 5;
    const int b  = blockIdx.y;
    const int q0 = q0blk + w * 32;

    const unsigned short* qrow = qb + ((size_t)(b*S) + q0 + lr) * DP + hi*8;
    bf16x8 qf0 = ldfrag(qrow);
    bf16x8 qf1 = ldfrag(qrow + 16);
    bf16x8 qf2 = ldfrag(qrow + 32);

    const unsigned short* kbase = kb + ((size_t)(b*S) + lr) * DP + hi*8;
    const unsigned short* vbase = vT + (size_t)lr*NROWS + (size_t)b*S + hi*8;

    f32x16 of0 = {0,0,0,0,0,0,0,0,0,0,0,0,0,0,0,0};
    f32x16 of1 = {0,0,0,0,0,0,0,0,0,0,0,0,0,0,0,0};
    float el = 0.f;

    const int bb = 127 - w*32 - lr + 4*hi;

    bf16x8 kfA[3], vfA[4], kfB[3], vfB[4];

    auto loadK = [&](int kt, bf16x8* kf) {
        const unsigned short* p = kbase + (size_t)kt*DP;
        kf[0] = ldfrag(p); kf[1] = ldfrag(p + 16); kf[2] = ldfrag(p + 32);
    };
    auto loadV = [&](int kt, bf16x8* vf) {
        const unsigned short* p = vbase + kt;
        vf[0] = ldfrag(p);
        vf[1] = ldfrag(p + 16);
        vf[2] = ldfrag(p + (size_t)32*NROWS);
        vf[3] = ldfrag(p + (size_t)32*NROWS + 16);
    };

    auto compute = [&](int ktl, const bf16x8* kf, const bf16x8* vf) {
        f32x16 c = {0,0,0,0,0,0,0,0,0,0,0,0,0,0,0,0};
        c = __builtin_amdgcn_mfma_f32_32x32x16_bf16(kf[0], qf0, c, 0,0,0);
        c = __builtin_amdgcn_mfma_f32_32x32x16_bf16(kf[1], qf1, c, 0,0,0);
        c = __builtin_amdgcn_mfma_f32_32x32x16_bf16(kf[2], qf2, c, 0,0,0);

        float e[16];
        #pragma unroll
        for (int r = 0; r < 16; ++r) {
            float s = c[r] + sbtw[bb + ktl + (r&3) + 8*(r>>2)];
            e[r] = __expf(s);
            el += e[r];
        }
        unsigned a0 = cvtpk(e[0],  e[1]);
        unsigned a1 = cvtpk(e[2],  e[3]);
        unsigned a2 = cvtpk(e[4],  e[5]);
        unsigned a3 = cvtpk(e[6],  e[7]);
        plswap(a0, a2);
        plswap(a1, a3);
        unsigned b0 = cvtpk(e[8],  e[9]);
        unsigned b1 = cvtpk(e[10], e[11]);
        unsigned b2 = cvtpk(e[12], e[13]);
        unsigned b3 = cvtpk(e[14], e[15]);
        plswap(b0, b2);
        plswap(b1, b3);
        uint4 u0 = {a0, a1, a2, a3};
        uint4 u1 = {b0, b1, b2, b3};
        bf16x8 pa0 = __builtin_bit_cast(bf16x8, u0);
        bf16x8 pa1 = __builtin_bit_cast(bf16x8, u1);

        of0 = __builtin_amdgcn_mfma_f32_32x32x16_bf16(pa0, vf[0], of0, 0,0,0);
        of0 = __builtin_amdgcn_mfma_f32_32x32x16_bf16(pa1, vf[1], of0, 0,0,0);
        of1 = __builtin_amdgcn_mfma_f32_32x32x16_bf16(pa0, vf[2], of1, 0,0,0);
        of1 = __builtin_amdgcn_mfma_f32_32x32x16_bf16(pa1, vf[3], of1, 0,0,0);
    };

    loadK(kt0, kfA); loadV(kt0, vfA);
    for (int kt = kt0; kt < kt0 + klen; kt += 64) {
        loadK(kt+32, kfB); loadV(kt+32, vfB);
        compute(kt - kt0, kfA, vfA);
        if (kt + 64 < kt0 + klen) { loadK(kt+64, kfA); loadV(kt+64, vfA); }
        compute(kt + 32 - kt0, kfB, vfB);
    }

    el += __shfl_xor(el, 32);

    // ---- write bf16 partials ----
    const size_t rowbase = (size_t)blockIdx.z * NROWS + b*S + q0;
    #pragma unroll
    for (int r = 0; r < 16; ++r) {
        int qr = (r&3) + 8*(r>>2) + 4*hi;
        unsigned short* pr = pob + (rowbase + qr) * XSTR;
        pr[lr] = f2bf(of0[r]);
        if (lr < 8) pr[32 + lr] = f2bf(of1[r]);
    }
    if (hi == 0) pl[rowbase + lr] = el;

    // ---- split-K arrival; last block does the fixup ----
    __threadfence();
    __syncthreads();
    if (tid == 0) {
        int old = atomicAdd(&cnt[b*NQT + blockIdx.x], 1);
        sdone = (old == nsplit - 1) ? 1 : 0;
    }
    __syncthreads();
    if (!sdone) return;
    __threadfence();

    // ---- fixup (k4 algebra): rows g = b*S + q0 + lr per wave ----
    const int g = b*S + q0 + lr;

    float lsum = 0.f;
    for (int s = 0; s < nsplit; ++s) lsum += pl[(size_t)s*NROWS + g];
    const float linv = 1.0f / lsum;

    float a[3][8];
    #pragma unroll
    for (int t = 0; t < 3; ++t)
        #pragma unroll
        for (int j = 0; j < 8; ++j) a[t][j] = 0.f;
    for (int s = 0; s < nsplit; ++s) {
        const unsigned short* pr = pob + ((size_t)s*NROWS + g) * XSTR;
        #pragma unroll
        for (int t = 0; t < 3; ++t) {
            if (t == 2 && hi == 1) continue;          // d = 40..47 unused
            uint4 u = *(const uint4*)(pr + t*16 + hi*8);
            a[t][0] += bf2f((unsigned short)(u.x)); a[t][1] += bf2f((unsigned short)(u.x >> 16));
            a[t][2] += bf2f((unsigned short)(u.y)); a[t][3] += bf2f((unsigned short)(u.y >> 16));
            a[t][4] += bf2f((unsigned short)(u.z)); a[t][5] += bf2f((unsigned short)(u.z >> 16));
            a[t][6] += bf2f((unsigned short)(u.w)); a[t][7] += bf2f((unsigned short)(u.w >> 16));
        }
    }
    bf16x8 ab[3];
    #pragma unroll
    for (int t = 0; t < 3; ++t) {
        uint4 u = { cvtpk(a[t][0]*linv, a[t][1]*linv), cvtpk(a[t][2]*linv, a[t][3]*linv),
                    cvtpk(a[t][4]*linv, a[t][5]*linv), cvtpk(a[t][6]*linv, a[t][7]*linv) };
        ab[t] = __builtin_bit_cast(bf16x8, u);
    }

    f32x16 c0 = {0,0,0,0,0,0,0,0,0,0,0,0,0,0,0,0};
    f32x16 c1 = {0,0,0,0,0,0,0,0,0,0,0,0,0,0,0,0};
    #pragma unroll
    for (int t = 0; t < 3; ++t) {
        c0 = __builtin_amdgcn_mfma_f32_32x32x16_bf16(ldfrag(woT + lr*48      + t*16 + hi*8), ab[t], c0, 0,0,0);
        c1 = __builtin_amdgcn_mfma_f32_32x32x16_bf16(ldfrag(woT + (32+lr)*48 + t*16 + hi*8), ab[t], c1, 0,0,0);
    }
    const unsigned short* xr = xb + (size_t)g*XSTR;
    #pragma unroll
    for (int rr = 0; rr < 4; ++rr) {
        ushort4 v = *(const ushort4*)(xr + rr*8 + 4*hi);
        c0[rr*4+0] += bf2f(v.x); c0[rr*4+1] += bf2f(v.y);
        c0[rr*4+2] += bf2f(v.z); c0[rr*4+3] += bf2f(v.w);
    }
    {
        ushort4 v = *(const ushort4*)(xr + 32 + 4*hi);
        c1[0] += bf2f(v.x); c1[1] += bf2f(v.y); c1[2] += bf2f(v.z); c1[3] += bf2f(v.w);
    }

    float ss = 0.f;
    #pragma unroll
    for (int r = 0; r < 16; ++r) ss += c0[r]*c0[r] + c1[r]*c1[r];
    ss += __shfl_xor(ss, 32);
    const float inv2 = rsqrtf(ss * (1.0f/D) + 1e-6f);

    f32x16 t0, t1;
    #pragma unroll
    for (int r = 0; r < 16; ++r) { t0[r] = c0[r]*inv2; t1[r] = c1[r]*inv2; }
    uint4 h0,h1,h2; repack_cl(t0, t1, h0, h1, h2);
    bf16x8 hb[3] = { __builtin_bit_cast(bf16x8, h0),
                     __builtin_bit_cast(bf16x8, h1),
                     __builtin_bit_cast(bf16x8, h2) };

    f32x16 d0 = {0,0,0,0,0,0,0,0,0,0,0,0,0,0,0,0};
    f32x16 d1 = {0,0,0,0,0,0,0,0,0,0,0,0,0,0,0,0};
    #pragma unroll
    for (int t = 0; t < 3; ++t) {
        d0 = __builtin_amdgcn_mfma_f32_32x32x16_bf16(ldfrag(wiT + lr*48      + t*16 + hi*8), hb[t], d0, 0,0,0);
        d1 = __builtin_amdgcn_mfma_f32_32x32x16_bf16(ldfrag(wiT + (32+lr)*48 + t*16 + hi*8), hb[t], d1, 0,0,0);
    }
    #pragma unroll
    for (int r = 0; r < 16; ++r) { d0[r] = fmaxf(d0[r], 0.f); d1[r] = fmaxf(d1[r], 0.f); }
    uint4 g0,g1,g2; repack_cl(d0, d1, g0, g1, g2);
    bf16x8 fb[3] = { __builtin_bit_cast(bf16x8, g0),
                     __builtin_bit_cast(bf16x8, g1),
                     __builtin_bit_cast(bf16x8, g2) };

    f32x16 e0 = {0,0,0,0,0,0,0,0,0,0,0,0,0,0,0,0};
    f32x16 e1 = {0,0,0,0,0,0,0,0,0,0,0,0,0,0,0,0};
    #pragma unroll
    for (int t = 0; t < 3; ++t) {
        e0 = __builtin_amdgcn_mfma_f32_32x32x16_bf16(ldfrag(wo2T + lr*48      + t*16 + hi*8), fb[t], e0, 0,0,0);
        e1 = __builtin_amdgcn_mfma_f32_32x32x16_bf16(ldfrag(wo2T + (32+lr)*48 + t*16 + hi*8), fb[t], e1, 0,0,0);
    }
    #pragma unroll
    for (int r = 0; r < 16; ++r) { e0[r] += c0[r]; e1[r] += c1[r]; }

    float ss2 = 0.f;
    #pragma unroll
    for (int r = 0; r < 16; ++r) ss2 += e0[r]*e0[r] + e1[r]*e1[r];
    ss2 += __shfl_xor(ss2, 32);
    const float inv3 = rsqrtf(ss2 * (1.0f/D) + 1e-6f);

    float* orow = out + (size_t)g * D;
    #pragma unroll
    for (int rr = 0; rr < 4; ++rr) {
        float4 lf = *(const float4*)(lnf + rr*8 + 4*hi);
        float4 v = { e0[rr*4+0]*inv3*lf.x, e0[rr*4+1]*inv3*lf.y,
                     e0[rr*4+2]*inv3*lf.z, e0[rr*4+3]*inv3*lf.w };
        *(float4*)(orow + rr*8 + 4*hi) = v;
    }
    {
        float4 lf = *(const float4*)(lnf + 32 + 4*hi);
        float4 v = { e1[0]*inv3*lf.x, e1[1]*inv3*lf.y, e1[2]*inv3*lf.z, e1[3]*inv3*lf.w };
        *(float4*)(orow + 32 + 4*hi) = v;
    }
}

extern "C" void kernel_launch(void* const* d_in, const int* in_sizes, int n_in,
                              void* d_out, int out_size, void* d_ws, size_t ws_size,
                              hipStream_t stream) {
    const float* embs = (const float*)d_in[0];
    const float* Wa   = (const float*)d_in[1];
    const float* ba   = (const float*)d_in[2];
    const float* ln1  = (const float*)d_in[3];
    const float* Wq   = (const float*)d_in[4];
    const float* Wk   = (const float*)d_in[5];
    const float* Wv   = (const float*)d_in[6];
    const float* Wo   = (const float*)d_in[7];
    const float* ln2  = (const float*)d_in[8];
    const float* wi   = (const float*)d_in[9];
    const float* wo   = (const float*)d_in[10];
    const float* lnf  = (const float*)d_in[11];
    const float* rb   = (const float*)d_in[12];

    char* wsb = (char*)d_ws;
    unsigned short* xb   = (unsigned short*)(wsb);              // NROWS*48*2 = 1,572,864
    unsigned short* qb   = (unsigned short*)(wsb + 1572864);    // 2,097,152
    unsigned short* kbq  = (unsigned short*)(wsb + 3670016);    // 2,097,152
    unsigned short* vT   = (unsigned short*)(wsb + 5767168);    // 2,097,152
    unsigned short* waT  = (unsigned short*)(wsb + 7864320);    // 18,432
    unsigned short* wqT  = (unsigned short*)(wsb + 7882752);    // 6,144
    unsigned short* wkT  = (unsigned short*)(wsb + 7888896);
    unsigned short* wvT  = (unsigned short*)(wsb + 7895040);
    unsigned short* woT  = (unsigned short*)(wsb + 7901184);
    unsigned short* wiT  = (unsigned short*)(wsb + 7907328);
    unsigned short* wo2T = (unsigned short*)(wsb + 7913472);
    const size_t base = 7919616;

    int nsplit = 8;
    while (nsplit > 1 &&
           base + (size_t)nsplit*(1572864 + 65536) + 16384 + 512 > ws_size)
        nsplit >>= 1;
    unsigned short* pob = (unsigned short*)(wsb + base);                     // nsplit * NROWS*48*2
    float* pl   = (float*)(wsb + base + (size_t)nsplit*1572864);             // nsplit * NROWS*4
    float* btab = (float*)(wsb + base + (size_t)nsplit*(1572864 + 65536));   // 16,384
    int*   cnt  = (int*)  (wsb + base + (size_t)nsplit*(1572864 + 65536) + 16384);  // 512
    int klen = S / nsplit;

    k0_prep<<<36, 256, 0, stream>>>(Wa, ba, ln1, Wq, Wk, Wv, Wo, ln2, wi, wo, rb,
                                    waT, wqT, wkT, wvT, woT, wiT, wo2T, btab, cnt);
    k1_adapter_qkv<<<NROWS/32, 64, 0, stream>>>(embs, waT, wqT, wkT, wvT, xb, qb, kbq, vT);
    k3_attn_fused<<<dim3(NQT, B, nsplit), 256, 0, stream>>>(
        qb, kbq, vT, btab, xb, woT, wiT, wo2T, lnf, pob, pl, cnt, (float*)d_out, klen, nsplit);
}

// Round 11
// 58.789 us; speedup vs baseline: 3.1272x; 3.1272x over previous
//
#include <hip/hip_runtime.h>
#include <hip/hip_bf16.h>
#include <math.h>

#define D 40
#define DIN 128
#define S 2048
#define B 8
#define NROWS (B*S)   // 16384
#define DP 64         // padded depth for Q/K bf16 rows
#define DVP 64        // padded depth (rows) for transposed V
#define XSTR 48       // xb / pob row stride (ushorts)

typedef __bf16 bf16x8 __attribute__((ext_vector_type(8)));
typedef float f32x4 __attribute__((ext_vector_type(4)));
typedef float f32x16 __attribute__((ext_vector_type(16)));

static __device__ __forceinline__ unsigned short f2bf(float f) {
    unsigned u = __builtin_bit_cast(unsigned, f);
    u += 0x7fff + ((u >> 16) & 1);   // RNE
    return (unsigned short)(u >> 16);
}
static __device__ __forceinline__ float bf2f(unsigned short h) {
    return __builtin_bit_cast(float, (unsigned)h << 16);
}
static __device__ __forceinline__ bf16x8 ldfrag(const unsigned short* p) {
    return __builtin_bit_cast(bf16x8, *(const uint4*)p);
}
static __device__ __forceinline__ unsigned cvtpk(float lo, float hi) {
    unsigned r;
    asm("v_cvt_pk_bf16_f32 %0, %1, %2" : "=v"(r) : "v"(lo), "v"(hi));
    return r;
}
static __device__ __forceinline__ void plswap(unsigned &a, unsigned &b) {
    asm("v_permlane32_swap_b32 %0, %1" : "+v"(a), "+v"(b));
}

// ---------------- Kernel 0: weight prep + bias table (fused) ----------------
__global__ __launch_bounds__(256) void k0_prep(
    const float* __restrict__ Wa, const float* __restrict__ ba, const float* __restrict__ ln1,
    const float* __restrict__ Wq, const float* __restrict__ Wk, const float* __restrict__ Wv,
    const float* __restrict__ Wo, const float* __restrict__ ln2,
    const float* __restrict__ wi, const float* __restrict__ wo,
    const float* __restrict__ rel_bias,
    unsigned short* __restrict__ waT, unsigned short* __restrict__ wqT,
    unsigned short* __restrict__ wkT, unsigned short* __restrict__ wvT,
    unsigned short* __restrict__ woT, unsigned short* __restrict__ wiT,
    unsigned short* __restrict__ wo2T, float* __restrict__ btab)
{
    int i = blockIdx.x * 256 + threadIdx.x;
    if (i < 64*144) {
        int col = i / 144, k = i - col*144;
        float v = 0.f;
        if (col < D) {
            if (k < DIN) v = Wa[k*D + col];
            else if (k == DIN) v = ba[col];
        }
        waT[i] = f2bf(v);
    }
    if (i < 64*48) {
        int col = i / 48, d = i - col*48;
        bool ok = (col < D && d < D);
        float s1 = ok ? ln1[d] : 0.f;
        float s2 = ok ? ln2[d] : 0.f;
        wqT[i]  = f2bf(ok ? Wq[d*D + col] * s1 : 0.f);
        wkT[i]  = f2bf(ok ? Wk[d*D + col] * s1 : 0.f);
        wvT[i]  = f2bf(ok ? Wv[d*D + col] * s1 : 0.f);
        woT[i]  = f2bf(ok ? Wo[d*D + col]      : 0.f);
        wiT[i]  = f2bf(ok ? wi[d*D + col] * s2 : 0.f);
        wo2T[i] = f2bf(ok ? wo[d*D + col]      : 0.f);
    }
    if (i < 2*S - 1) {
        int rel = i - (S - 1);          // rel = k - q
        int bucket = (rel > 0) ? 16 : 0;
        int ar = rel < 0 ? -rel : rel;
        int add;
        if (ar < 8) {
            add = ar;
        } else {
            float tt = logf((float)ar * 0.125f) / logf(16.0f) * 8.0f;
            int lg = 8 + (int)tt;
            add = lg < 15 ? lg : 15;
        }
        btab[i] = rel_bias[bucket + add];
    }
}

// C-layout -> row-major bf16 frags (validated in k1/k3/k4):
static __device__ __forceinline__ void repack_cl(
    const f32x16& t0, const f32x16& t1, uint4& u0, uint4& u1, uint4& u2)
{
    unsigned a0=cvtpk(t0[0],t0[1]),  a1=cvtpk(t0[2],t0[3]),
             a2=cvtpk(t0[4],t0[5]),  a3=cvtpk(t0[6],t0[7]);
    plswap(a0,a2); plswap(a1,a3);
    unsigned b0=cvtpk(t0[8],t0[9]),  b1=cvtpk(t0[10],t0[11]),
             b2=cvtpk(t0[12],t0[13]),b3=cvtpk(t0[14],t0[15]);
    plswap(b0,b2); plswap(b1,b3);
    unsigned c0=cvtpk(t1[0],t1[1]),  c1=cvtpk(t1[2],t1[3]),
             c2=cvtpk(t1[4],t1[5]),  c3=cvtpk(t1[6],t1[7]);
    plswap(c0,c2); plswap(c1,c3);
    u0 = (uint4){a0,a1,a2,a3}; u1 = (uint4){b0,b1,b2,b3}; u2 = (uint4){c0,c1,c2,c3};
}

// ---------------- Kernel 1: adapter + rmsnorm + QKV, all-MFMA ----------------
__global__ __launch_bounds__(64) void k1_adapter_qkv(
    const float* __restrict__ embs,
    const unsigned short* __restrict__ waT, const unsigned short* __restrict__ wqT,
    const unsigned short* __restrict__ wkT, const unsigned short* __restrict__ wvT,
    unsigned short* __restrict__ xb, unsigned short* __restrict__ qb,
    unsigned short* __restrict__ kbq, unsigned short* __restrict__ vT)
{
    const int l  = threadIdx.x;
    const int lr = l & 31, hi = l >> 5;
    const int row = blockIdx.x * 32 + lr;

    const float* erow = embs + (size_t)row * DIN;
    bf16x8 eb[9];
    #pragma unroll
    for (int kk = 0; kk < 8; ++kk) {
        float4 f0 = *(const float4*)(erow + kk*16 + hi*8);
        float4 f1 = *(const float4*)(erow + kk*16 + hi*8 + 4);
        uint4 u = { cvtpk(f0.x, f0.y), cvtpk(f0.z, f0.w),
                    cvtpk(f1.x, f1.y), cvtpk(f1.z, f1.w) };
        eb[kk] = __builtin_bit_cast(bf16x8, u);
    }
    {
        uint4 u = { hi == 0 ? 0x3f80u : 0u, 0u, 0u, 0u };
        eb[8] = __builtin_bit_cast(bf16x8, u);
    }

    f32x16 x0 = {0,0,0,0,0,0,0,0,0,0,0,0,0,0,0,0};
    f32x16 x1 = {0,0,0,0,0,0,0,0,0,0,0,0,0,0,0,0};
    #pragma unroll
    for (int kk = 0; kk < 9; ++kk) {
        bf16x8 a0 = ldfrag(waT + lr*144      + kk*16 + hi*8);
        bf16x8 a1 = ldfrag(waT + (32+lr)*144 + kk*16 + hi*8);
        x0 = __builtin_amdgcn_mfma_f32_32x32x16_bf16(a0, eb[kk], x0, 0,0,0);
        x1 = __builtin_amdgcn_mfma_f32_32x32x16_bf16(a1, eb[kk], x1, 0,0,0);
    }

    float ss = 0.f;
    #pragma unroll
    for (int r = 0; r < 16; ++r) {
        x0[r] = fmaxf(x0[r], 0.f);
        x1[r] = fmaxf(x1[r], 0.f);
        ss += x0[r]*x0[r] + x1[r]*x1[r];
    }
    ss += __shfl_xor(ss, 32);
    const float inv = rsqrtf(ss * (1.0f/D) + 1e-6f);

    {
        uint4 u0,u1,u2; repack_cl(x0, x1, u0, u1, u2);
        unsigned short* p = xb + (size_t)row*XSTR;
        *(uint4*)(p + hi*8)      = u0;
        *(uint4*)(p + 16 + hi*8) = u1;
        *(uint4*)(p + 32 + hi*8) = u2;
    }

    #pragma unroll
    for (int r = 0; r < 16; ++r) { x0[r] *= inv; x1[r] *= inv; }
    uint4 h0,h1,h2; repack_cl(x0, x1, h0, h1, h2);
    bf16x8 hb[3] = { __builtin_bit_cast(bf16x8, h0),
                     __builtin_bit_cast(bf16x8, h1),
                     __builtin_bit_cast(bf16x8, h2) };

    f32x16 qa0={0,0,0,0,0,0,0,0,0,0,0,0,0,0,0,0}, qa1={0,0,0,0,0,0,0,0,0,0,0,0,0,0,0,0};
    f32x16 ka0={0,0,0,0,0,0,0,0,0,0,0,0,0,0,0,0}, ka1={0,0,0,0,0,0,0,0,0,0,0,0,0,0,0,0};
    f32x16 va0={0,0,0,0,0,0,0,0,0,0,0,0,0,0,0,0}, va1={0,0,0,0,0,0,0,0,0,0,0,0,0,0,0,0};
    #pragma unroll
    for (int t = 0; t < 3; ++t) {
        bf16x8 h = hb[t];
        qa0 = __builtin_amdgcn_mfma_f32_32x32x16_bf16(ldfrag(wqT + lr*48      + t*16 + hi*8), h, qa0, 0,0,0);
        qa1 = __builtin_amdgcn_mfma_f32_32x32x16_bf16(ldfrag(wqT + (32+lr)*48 + t*16 + hi*8), h, qa1, 0,0,0);
        ka0 = __builtin_amdgcn_mfma_f32_32x32x16_bf16(ldfrag(wkT + lr*48      + t*16 + hi*8), h, ka0, 0,0,0);
        ka1 = __builtin_amdgcn_mfma_f32_32x32x16_bf16(ldfrag(wkT + (32+lr)*48 + t*16 + hi*8), h, ka1, 0,0,0);
        va0 = __builtin_amdgcn_mfma_f32_32x32x16_bf16(ldfrag(wvT + lr*48      + t*16 + hi*8), h, va0, 0,0,0);
        va1 = __builtin_amdgcn_mfma_f32_32x32x16_bf16(ldfrag(wvT + (32+lr)*48 + t*16 + hi*8), h, va1, 0,0,0);
    }

    {
        uint4 u0,u1,u2; repack_cl(qa0, qa1, u0, u1, u2);
        unsigned short* p = qb + (size_t)row*DP;
        *(uint4*)(p + hi*8) = u0; *(uint4*)(p + 16 + hi*8) = u1; *(uint4*)(p + 32 + hi*8) = u2;
    }
    {
        uint4 u0,u1,u2; repack_cl(ka0, ka1, u0, u1, u2);
        unsigned short* p = kbq + (size_t)row*DP;
        *(uint4*)(p + hi*8) = u0; *(uint4*)(p + 16 + hi*8) = u1; *(uint4*)(p + 32 + hi*8) = u2;
    }
    #pragma unroll
    for (int r = 0; r < 16; ++r) {
        int col = (r&3) + 8*(r>>2) + 4*hi;
        vT[(size_t)col*NROWS + row] = f2bf(va0[r]);
        if (r < 4) vT[(size_t)(32 + (r&3) + 4*hi)*NROWS + row] = f2bf(va1[r]);
    }
    #pragma unroll
    for (int c = 0; c < 12; ++c) {
        vT[(size_t)(D + 2*c + hi)*NROWS + row] = 0;
    }
}

// ---------------- Kernel 3: flash attention, swapped-QK^T 32x32 MFMA ----------------
__global__ __launch_bounds__(256) void k3_attn_mfma(
    const unsigned short* __restrict__ qb, const unsigned short* __restrict__ kb,
    const unsigned short* __restrict__ vT, const float* __restrict__ btab,
    unsigned short* __restrict__ pob, float* __restrict__ pl, int klen)
{
    __shared__ float sbtw[2176 + 16];

    const int q0blk = blockIdx.x * 128;
    const int kt0   = blockIdx.z * klen;
    const int woff  = (S-1) + kt0 - q0blk - 127;

    int tid = threadIdx.x;
    for (int i = tid; i < klen + 128; i += 256) {
        int g = woff + i;
        sbtw[i] = btab[g < 0 ? 0 : (g > 4094 ? 4094 : g)];
    }
    __syncthreads();

    const int w  = tid >> 6, l = tid & 63;
    const int lr = l & 31,  hi = l >> 5;
    const int b  = blockIdx.y;
    const int q0 = q0blk + w * 32;

    const unsigned short* qrow = qb + ((size_t)(b*S) + q0 + lr) * DP + hi*8;
    bf16x8 qf0 = ldfrag(qrow);
    bf16x8 qf1 = ldfrag(qrow + 16);
    bf16x8 qf2 = ldfrag(qrow + 32);

    const unsigned short* kbase = kb + ((size_t)(b*S) + lr) * DP + hi*8;
    const unsigned short* vbase = vT + (size_t)lr*NROWS + (size_t)b*S + hi*8;

    f32x16 of0 = {0,0,0,0,0,0,0,0,0,0,0,0,0,0,0,0};
    f32x16 of1 = {0,0,0,0,0,0,0,0,0,0,0,0,0,0,0,0};
    float el = 0.f;

    const int bb = 127 - w*32 - lr + 4*hi;

    bf16x8 kfA[3], vfA[4], kfB[3], vfB[4];

    auto loadK = [&](int kt, bf16x8* kf) {
        const unsigned short* p = kbase + (size_t)kt*DP;
        kf[0] = ldfrag(p); kf[1] = ldfrag(p + 16); kf[2] = ldfrag(p + 32);
    };
    auto loadV = [&](int kt, bf16x8* vf) {
        const unsigned short* p = vbase + kt;
        vf[0] = ldfrag(p);
        vf[1] = ldfrag(p + 16);
        vf[2] = ldfrag(p + (size_t)32*NROWS);
        vf[3] = ldfrag(p + (size_t)32*NROWS + 16);
    };

    auto compute = [&](int ktl, const bf16x8* kf, const bf16x8* vf) {
        f32x16 c = {0,0,0,0,0,0,0,0,0,0,0,0,0,0,0,0};
        c = __builtin_amdgcn_mfma_f32_32x32x16_bf16(kf[0], qf0, c, 0,0,0);
        c = __builtin_amdgcn_mfma_f32_32x32x16_bf16(kf[1], qf1, c, 0,0,0);
        c = __builtin_amdgcn_mfma_f32_32x32x16_bf16(kf[2], qf2, c, 0,0,0);

        float e[16];
        #pragma unroll
        for (int r = 0; r < 16; ++r) {
            float s = c[r] + sbtw[bb + ktl + (r&3) + 8*(r>>2)];
            e[r] = __expf(s);
            el += e[r];
        }
        unsigned a0 = cvtpk(e[0],  e[1]);
        unsigned a1 = cvtpk(e[2],  e[3]);
        unsigned a2 = cvtpk(e[4],  e[5]);
        unsigned a3 = cvtpk(e[6],  e[7]);
        plswap(a0, a2);
        plswap(a1, a3);
        unsigned b0 = cvtpk(e[8],  e[9]);
        unsigned b1 = cvtpk(e[10], e[11]);
        unsigned b2 = cvtpk(e[12], e[13]);
        unsigned b3 = cvtpk(e[14], e[15]);
        plswap(b0, b2);
        plswap(b1, b3);
        uint4 u0 = {a0, a1, a2, a3};
        uint4 u1 = {b0, b1, b2, b3};
        bf16x8 pa0 = __builtin_bit_cast(bf16x8, u0);
        bf16x8 pa1 = __builtin_bit_cast(bf16x8, u1);

        of0 = __builtin_amdgcn_mfma_f32_32x32x16_bf16(pa0, vf[0], of0, 0,0,0);
        of0 = __builtin_amdgcn_mfma_f32_32x32x16_bf16(pa1, vf[1], of0, 0,0,0);
        of1 = __builtin_amdgcn_mfma_f32_32x32x16_bf16(pa0, vf[2], of1, 0,0,0);
        of1 = __builtin_amdgcn_mfma_f32_32x32x16_bf16(pa1, vf[3], of1, 0,0,0);
    };

    loadK(kt0, kfA); loadV(kt0, vfA);
    for (int kt = kt0; kt < kt0 + klen; kt += 64) {
        loadK(kt+32, kfB); loadV(kt+32, vfB);
        compute(kt - kt0, kfA, vfA);
        if (kt + 64 < kt0 + klen) { loadK(kt+64, kfA); loadV(kt+64, vfA); }
        compute(kt + 32 - kt0, kfB, vfB);
    }

    el += __shfl_xor(el, 32);

    // bf16 partials (stride 48): halves split-K round-trip traffic
    const size_t rowbase = (size_t)blockIdx.z * NROWS + b*S + q0;
    #pragma unroll
    for (int r = 0; r < 16; ++r) {
        int qr = (r&3) + 8*(r>>2) + 4*hi;
        unsigned short* pr = pob + (rowbase + qr) * XSTR;
        pr[lr] = f2bf(of0[r]);
        if (lr < 8) pr[32 + lr] = f2bf(of1[r]);
    }
    if (hi == 0) pl[rowbase + lr] = el;
}

// ---------------- Kernel 4: combine + O-proj + residual + FF + rmsnorm, all-MFMA ----------------
__global__ __launch_bounds__(64) void k4_out_ff(
    const unsigned short* __restrict__ xb, const unsigned short* __restrict__ pob,
    const float* __restrict__ pl,
    const unsigned short* __restrict__ woT, const unsigned short* __restrict__ wiT,
    const unsigned short* __restrict__ wo2T, const float* __restrict__ lnf,
    float* __restrict__ out, int nsplit)
{
    const int l  = threadIdx.x;
    const int lr = l & 31, hi = l >> 5;
    const int row = blockIdx.x * 32 + lr;

    float lsum = 0.f;
    for (int s = 0; s < nsplit; ++s) lsum += pl[(size_t)s*NROWS + row];
    const float linv = 1.0f / lsum;

    float a[3][8];
    #pragma unroll
    for (int t = 0; t < 3; ++t)
        #pragma unroll
        for (int j = 0; j < 8; ++j) a[t][j] = 0.f;
    for (int s = 0; s < nsplit; ++s) {
        const unsigned short* pr = pob + ((size_t)s*NROWS + row) * XSTR;
        #pragma unroll
        for (int t = 0; t < 3; ++t) {
            if (t == 2 && hi == 1) continue;          // d = 40..47 unused
            uint4 u = *(const uint4*)(pr + t*16 + hi*8);
            a[t][0] += bf2f((unsigned short)(u.x)); a[t][1] += bf2f((unsigned short)(u.x >> 16));
            a[t][2] += bf2f((unsigned short)(u.y)); a[t][3] += bf2f((unsigned short)(u.y >> 16));
            a[t][4] += bf2f((unsigned short)(u.z)); a[t][5] += bf2f((unsigned short)(u.z >> 16));
            a[t][6] += bf2f((unsigned short)(u.w)); a[t][7] += bf2f((unsigned short)(u.w >> 16));
        }
    }
    bf16x8 ab[3];
    #pragma unroll
    for (int t = 0; t < 3; ++t) {
        uint4 u = { cvtpk(a[t][0]*linv, a[t][1]*linv), cvtpk(a[t][2]*linv, a[t][3]*linv),
                    cvtpk(a[t][4]*linv, a[t][5]*linv), cvtpk(a[t][6]*linv, a[t][7]*linv) };
        ab[t] = __builtin_bit_cast(bf16x8, u);
    }

    f32x16 c0 = {0,0,0,0,0,0,0,0,0,0,0,0,0,0,0,0};
    f32x16 c1 = {0,0,0,0,0,0,0,0,0,0,0,0,0,0,0,0};
    #pragma unroll
    for (int t = 0; t < 3; ++t) {
        c0 = __builtin_amdgcn_mfma_f32_32x32x16_bf16(ldfrag(woT + lr*48      + t*16 + hi*8), ab[t], c0, 0,0,0);
        c1 = __builtin_amdgcn_mfma_f32_32x32x16_bf16(ldfrag(woT + (32+lr)*48 + t*16 + hi*8), ab[t], c1, 0,0,0);
    }
    const unsigned short* xr = xb + (size_t)row*XSTR;
    #pragma unroll
    for (int rr = 0; rr < 4; ++rr) {
        ushort4 v = *(const ushort4*)(xr + rr*8 + 4*hi);
        c0[rr*4+0] += bf2f(v.x); c0[rr*4+1] += bf2f(v.y);
        c0[rr*4+2] += bf2f(v.z); c0[rr*4+3] += bf2f(v.w);
    }
    {
        ushort4 v = *(const ushort4*)(xr + 32 + 4*hi);
        c1[0] += bf2f(v.x); c1[1] += bf2f(v.y); c1[2] += bf2f(v.z); c1[3] += bf2f(v.w);
    }

    float ss = 0.f;
    #pragma unroll
    for (int r = 0; r < 16; ++r) ss += c0[r]*c0[r] + c1[r]*c1[r];
    ss += __shfl_xor(ss, 32);
    const float inv2 = rsqrtf(ss * (1.0f/D) + 1e-6f);

    f32x16 t0, t1;
    #pragma unroll
    for (int r = 0; r < 16; ++r) { t0[r] = c0[r]*inv2; t1[r] = c1[r]*inv2; }
    uint4 h0,h1,h2; repack_cl(t0, t1, h0, h1, h2);
    bf16x8 hb[3] = { __builtin_bit_cast(bf16x8, h0),
                     __builtin_bit_cast(bf16x8, h1),
                     __builtin_bit_cast(bf16x8, h2) };

    f32x16 d0 = {0,0,0,0,0,0,0,0,0,0,0,0,0,0,0,0};
    f32x16 d1 = {0,0,0,0,0,0,0,0,0,0,0,0,0,0,0,0};
    #pragma unroll
    for (int t = 0; t < 3; ++t) {
        d0 = __builtin_amdgcn_mfma_f32_32x32x16_bf16(ldfrag(wiT + lr*48      + t*16 + hi*8), hb[t], d0, 0,0,0);
        d1 = __builtin_amdgcn_mfma_f32_32x32x16_bf16(ldfrag(wiT + (32+lr)*48 + t*16 + hi*8), hb[t], d1, 0,0,0);
    }
    #pragma unroll
    for (int r = 0; r < 16; ++r) { d0[r] = fmaxf(d0[r], 0.f); d1[r] = fmaxf(d1[r], 0.f); }
    uint4 g0,g1,g2; repack_cl(d0, d1, g0, g1, g2);
    bf16x8 fb[3] = { __builtin_bit_cast(bf16x8, g0),
                     __builtin_bit_cast(bf16x8, g1),
                     __builtin_bit_cast(bf16x8, g2) };

    f32x16 e0 = {0,0,0,0,0,0,0,0,0,0,0,0,0,0,0,0};
    f32x16 e1 = {0,0,0,0,0,0,0,0,0,0,0,0,0,0,0,0};
    #pragma unroll
    for (int t = 0; t < 3; ++t) {
        e0 = __builtin_amdgcn_mfma_f32_32x32x16_bf16(ldfrag(wo2T + lr*48      + t*16 + hi*8), fb[t], e0, 0,0,0);
        e1 = __builtin_amdgcn_mfma_f32_32x32x16_bf16(ldfrag(wo2T + (32+lr)*48 + t*16 + hi*8), fb[t], e1, 0,0,0);
    }
    #pragma unroll
    for (int r = 0; r < 16; ++r) { e0[r] += c0[r]; e1[r] += c1[r]; }

    float ss2 = 0.f;
    #pragma unroll
    for (int r = 0; r < 16; ++r) ss2 += e0[r]*e0[r] + e1[r]*e1[r];
    ss2 += __shfl_xor(ss2, 32);
    const float inv3 = rsqrtf(ss2 * (1.0f/D) + 1e-6f);

    float* orow = out + (size_t)row * D;
    #pragma unroll
    for (int rr = 0; rr < 4; ++rr) {
        float4 lf = *(const float4*)(lnf + rr*8 + 4*hi);
        float4 v = { e0[rr*4+0]*inv3*lf.x, e0[rr*4+1]*inv3*lf.y,
                     e0[rr*4+2]*inv3*lf.z, e0[rr*4+3]*inv3*lf.w };
        *(float4*)(orow + rr*8 + 4*hi) = v;
    }
    {
        float4 lf = *(const float4*)(lnf + 32 + 4*hi);
        float4 v = { e1[0]*inv3*lf.x, e1[1]*inv3*lf.y, e1[2]*inv3*lf.z, e1[3]*inv3*lf.w };
        *(float4*)(orow + 32 + 4*hi) = v;
    }
}

extern "C" void kernel_launch(void* const* d_in, const int* in_sizes, int n_in,
                              void* d_out, int out_size, void* d_ws, size_t ws_size,
                              hipStream_t stream) {
    const float* embs = (const float*)d_in[0];
    const float* Wa   = (const float*)d_in[1];
    const float* ba   = (const float*)d_in[2];
    const float* ln1  = (const float*)d_in[3];
    const float* Wq   = (const float*)d_in[4];
    const float* Wk   = (const float*)d_in[5];
    const float* Wv   = (const float*)d_in[6];
    const float* Wo   = (const float*)d_in[7];
    const float* ln2  = (const float*)d_in[8];
    const float* wi   = (const float*)d_in[9];
    const float* wo   = (const float*)d_in[10];
    const float* lnf  = (const float*)d_in[11];
    const float* rb   = (const float*)d_in[12];

    char* wsb = (char*)d_ws;
    unsigned short* xb   = (unsigned short*)(wsb);              // NROWS*48*2 = 1,572,864
    unsigned short* qb   = (unsigned short*)(wsb + 1572864);    // 2,097,152
    unsigned short* kbq  = (unsigned short*)(wsb + 3670016);    // 2,097,152
    unsigned short* vT   = (unsigned short*)(wsb + 5767168);    // 2,097,152
    unsigned short* waT  = (unsigned short*)(wsb + 7864320);    // 18,432
    unsigned short* wqT  = (unsigned short*)(wsb + 7882752);    // 6,144
    unsigned short* wkT  = (unsigned short*)(wsb + 7888896);
    unsigned short* wvT  = (unsigned short*)(wsb + 7895040);
    unsigned short* woT  = (unsigned short*)(wsb + 7901184);
    unsigned short* wiT  = (unsigned short*)(wsb + 7907328);
    unsigned short* wo2T = (unsigned short*)(wsb + 7913472);
    const size_t base = 7919616;

    int nsplit = 8;
    while (nsplit > 1 &&
           base + (size_t)nsplit*(1572864 + 65536) + 16384 > ws_size)
        nsplit >>= 1;
    unsigned short* pob = (unsigned short*)(wsb + base);                     // nsplit * NROWS*48*2
    float* pl   = (float*)(wsb + base + (size_t)nsplit*1572864);             // nsplit * NROWS*4
    float* btab = (float*)(wsb + base + (size_t)nsplit*(1572864 + 65536));   // 16,384
    int klen = S / nsplit;

    k0_prep<<<36, 256, 0, stream>>>(Wa, ba, ln1, Wq, Wk, Wv, Wo, ln2, wi, wo, rb,
                                    waT, wqT, wkT, wvT, woT, wiT, wo2T, btab);
    k1_adapter_qkv<<<NROWS/32, 64, 0, stream>>>(embs, waT, wqT, wkT, wvT, xb, qb, kbq, vT);
    k3_attn_mfma<<<dim3(S/128, B, nsplit), 256, 0, stream>>>(qb, kbq, vT, btab, pob, pl, klen);
    k4_out_ff<<<NROWS/32, 64, 0, stream>>>(xb, pob, pl, woT, wiT, wo2T, lnf, (float*)d_out, nsplit);
}

// Round 12
// 58.615 us; speedup vs baseline: 3.1365x; 1.0030x over previous
//
#include <hip/hip_runtime.h>
#include <hip/hip_bf16.h>
#include <math.h>

#define D 40
#define DIN 128
#define S 2048
#define B 8
#define NROWS (B*S)   // 16384
#define DP 64         // padded depth for Q/K bf16 rows
#define XSTR 48       // xb / pob row stride (ushorts)

typedef __bf16 bf16x8 __attribute__((ext_vector_type(8)));
typedef float f32x16 __attribute__((ext_vector_type(16)));

static __device__ __forceinline__ unsigned short f2bf(float f) {
    unsigned u = __builtin_bit_cast(unsigned, f);
    u += 0x7fff + ((u >> 16) & 1);   // RNE
    return (unsigned short)(u >> 16);
}
static __device__ __forceinline__ float bf2f(unsigned short h) {
    return __builtin_bit_cast(float, (unsigned)h << 16);
}
static __device__ __forceinline__ bf16x8 ldfrag(const unsigned short* p) {
    return __builtin_bit_cast(bf16x8, *(const uint4*)p);
}
static __device__ __forceinline__ unsigned cvtpk(float lo, float hi) {
    unsigned r;
    asm("v_cvt_pk_bf16_f32 %0, %1, %2" : "=v"(r) : "v"(lo), "v"(hi));
    return r;
}
static __device__ __forceinline__ void plswap(unsigned &a, unsigned &b) {
    asm("v_permlane32_swap_b32 %0, %1" : "+v"(a), "+v"(b));
}

// ---------------- Kernel 0: weight prep + bias table (fused) ----------------
__global__ __launch_bounds__(256) void k0_prep(
    const float* __restrict__ Wa, const float* __restrict__ ba, const float* __restrict__ ln1,
    const float* __restrict__ Wq, const float* __restrict__ Wk, const float* __restrict__ Wv,
    const float* __restrict__ Wo, const float* __restrict__ ln2,
    const float* __restrict__ wi, const float* __restrict__ wo,
    const float* __restrict__ rel_bias,
    unsigned short* __restrict__ waT, unsigned short* __restrict__ wqT,
    unsigned short* __restrict__ wkT, unsigned short* __restrict__ wvT,
    unsigned short* __restrict__ woT, unsigned short* __restrict__ wiT,
    unsigned short* __restrict__ wo2T, float* __restrict__ btab)
{
    int i = blockIdx.x * 256 + threadIdx.x;
    if (i < 64*144) {
        int col = i / 144, k = i - col*144;
        float v = 0.f;
        if (col < D) {
            if (k < DIN) v = Wa[k*D + col];
            else if (k == DIN) v = ba[col];
        }
        waT[i] = f2bf(v);
    }
    if (i < 64*48) {
        int col = i / 48, d = i - col*48;
        bool ok = (col < D && d < D);
        float s1 = ok ? ln1[d] : 0.f;
        float s2 = ok ? ln2[d] : 0.f;
        wqT[i]  = f2bf(ok ? Wq[d*D + col] * s1 : 0.f);
        wkT[i]  = f2bf(ok ? Wk[d*D + col] * s1 : 0.f);
        wvT[i]  = f2bf(ok ? Wv[d*D + col] * s1 : 0.f);
        woT[i]  = f2bf(ok ? Wo[d*D + col]      : 0.f);
        wiT[i]  = f2bf(ok ? wi[d*D + col] * s2 : 0.f);
        wo2T[i] = f2bf(ok ? wo[d*D + col]      : 0.f);
    }
    if (i < 2*S - 1) {
        int rel = i - (S - 1);          // rel = k - q
        int bucket = (rel > 0) ? 16 : 0;
        int ar = rel < 0 ? -rel : rel;
        int add;
        if (ar < 8) {
            add = ar;
        } else {
            float tt = logf((float)ar * 0.125f) / logf(16.0f) * 8.0f;
            int lg = 8 + (int)tt;
            add = lg < 15 ? lg : 15;
        }
        btab[i] = rel_bias[bucket + add];
    }
}

// Single-tile C-layout -> row-major bf16 frags (the u0/u1 halves of the
// validated repack_cl): u0 = cols tilebase+hi*8..+7, u1 = tilebase+16+hi*8..+7.
static __device__ __forceinline__ void repack1(const f32x16& t0, uint4& u0, uint4& u1)
{
    unsigned a0=cvtpk(t0[0],t0[1]),  a1=cvtpk(t0[2],t0[3]),
             a2=cvtpk(t0[4],t0[5]),  a3=cvtpk(t0[6],t0[7]);
    plswap(a0,a2); plswap(a1,a3);
    unsigned b0=cvtpk(t0[8],t0[9]),  b1=cvtpk(t0[10],t0[11]),
             b2=cvtpk(t0[12],t0[13]),b3=cvtpk(t0[14],t0[15]);
    plswap(b0,b2); plswap(b1,b3);
    u0 = (uint4){a0,a1,a2,a3}; u1 = (uint4){b0,b1,b2,b3};
}

// ---------------- Kernel 1: adapter + rmsnorm + QKV, all-MFMA, 2-wave col-split ----------------
// 512 blocks x 128 threads; wave w owns output-col tile w (32 cols) of the same
// 32 rows. Cross-wave: rmsnorm partials + normalized activations via LDS.
__global__ __launch_bounds__(128) void k1_adapter_qkv(
    const float* __restrict__ embs,
    const unsigned short* __restrict__ waT, const unsigned short* __restrict__ wqT,
    const unsigned short* __restrict__ wkT, const unsigned short* __restrict__ wvT,
    unsigned short* __restrict__ xb, unsigned short* __restrict__ qb,
    unsigned short* __restrict__ kbq, unsigned short* __restrict__ vT)
{
    __shared__ unsigned short sX[32][56];
    __shared__ float sSS[2][32];

    const int tid = threadIdx.x;
    const int w   = tid >> 6;
    const int l   = tid & 63;
    const int lr  = l & 31, hi = l >> 5;
    const int row = blockIdx.x * 32 + lr;
    const int cb  = w * 32;                 // this wave's col-tile base

    // E B-frags (both waves load same rows; 2nd wave hits L1/L2)
    const float* erow = embs + (size_t)row * DIN;
    bf16x8 eb[9];
    #pragma unroll
    for (int kk = 0; kk < 8; ++kk) {
        float4 f0 = *(const float4*)(erow + kk*16 + hi*8);
        float4 f1 = *(const float4*)(erow + kk*16 + hi*8 + 4);
        uint4 u = { cvtpk(f0.x, f0.y), cvtpk(f0.z, f0.w),
                    cvtpk(f1.x, f1.y), cvtpk(f1.z, f1.w) };
        eb[kk] = __builtin_bit_cast(bf16x8, u);
    }
    {
        uint4 u = { hi == 0 ? 0x3f80u : 0u, 0u, 0u, 0u };
        eb[8] = __builtin_bit_cast(bf16x8, u);
    }

    // adapter: this wave's 32-col tile
    f32x16 x0 = {0,0,0,0,0,0,0,0,0,0,0,0,0,0,0,0};
    #pragma unroll
    for (int kk = 0; kk < 9; ++kk) {
        bf16x8 a0 = ldfrag(waT + (size_t)(cb + lr)*144 + kk*16 + hi*8);
        x0 = __builtin_amdgcn_mfma_f32_32x32x16_bf16(a0, eb[kk], x0, 0,0,0);
    }

    float ss = 0.f;
    #pragma unroll
    for (int r = 0; r < 16; ++r) {
        x0[r] = fmaxf(x0[r], 0.f);
        ss += x0[r]*x0[r];
    }
    ss += __shfl_xor(ss, 32);
    if (hi == 0) sSS[w][lr] = ss;
    __syncthreads();
    const float inv = rsqrtf((sSS[0][lr] + sSS[1][lr]) * (1.0f/D) + 1e-6f);

    // residual xb (pre-norm)
    {
        uint4 u0, u1; repack1(x0, u0, u1);
        unsigned short* p = xb + (size_t)row*XSTR;
        *(uint4*)(p + cb + hi*8) = u0;
        if (w == 0) *(uint4*)(p + 16 + hi*8) = u1;
    }

    // H = x * inv -> LDS exchange -> full 48-d B-frags
    f32x16 xh;
    #pragma unroll
    for (int r = 0; r < 16; ++r) xh[r] = x0[r] * inv;
    {
        uint4 u0, u1; repack1(xh, u0, u1);
        *(uint4*)(&sX[lr][cb + hi*8]) = u0;
        if (w == 0) *(uint4*)(&sX[lr][16 + hi*8]) = u1;
    }
    __syncthreads();
    bf16x8 hb[3];
    #pragma unroll
    for (int t = 0; t < 3; ++t) hb[t] = ldfrag(&sX[lr][t*16 + hi*8]);

    // QKV: this wave's col tile of each projection (3 MFMAs each)
    f32x16 qa={0,0,0,0,0,0,0,0,0,0,0,0,0,0,0,0};
    f32x16 ka={0,0,0,0,0,0,0,0,0,0,0,0,0,0,0,0};
    f32x16 va={0,0,0,0,0,0,0,0,0,0,0,0,0,0,0,0};
    #pragma unroll
    for (int t = 0; t < 3; ++t) {
        bf16x8 h = hb[t];
        qa = __builtin_amdgcn_mfma_f32_32x32x16_bf16(ldfrag(wqT + (size_t)(cb+lr)*48 + t*16 + hi*8), h, qa, 0,0,0);
        ka = __builtin_amdgcn_mfma_f32_32x32x16_bf16(ldfrag(wkT + (size_t)(cb+lr)*48 + t*16 + hi*8), h, ka, 0,0,0);
        va = __builtin_amdgcn_mfma_f32_32x32x16_bf16(ldfrag(wvT + (size_t)(cb+lr)*48 + t*16 + hi*8), h, va, 0,0,0);
    }

    {
        uint4 u0, u1; repack1(qa, u0, u1);
        unsigned short* p = qb + (size_t)row*DP;
        *(uint4*)(p + cb + hi*8) = u0;
        if (w == 0) *(uint4*)(p + 16 + hi*8) = u1;
    }
    {
        uint4 u0, u1; repack1(ka, u0, u1);
        unsigned short* p = kbq + (size_t)row*DP;
        *(uint4*)(p + cb + hi*8) = u0;
        if (w == 0) *(uint4*)(p + 16 + hi*8) = u1;
    }
    // vT: 16 C-regs cover cols cb..cb+31 (wave1's include the zero pads 40..63)
    #pragma unroll
    for (int r = 0; r < 16; ++r) {
        int col = cb + (r&3) + 8*(r>>2) + 4*hi;
        vT[(size_t)col*NROWS + row] = f2bf(va[r]);
    }
}

// ---------------- Kernel 3: flash attention, swapped-QK^T 32x32 MFMA ----------------
__global__ __launch_bounds__(256) void k3_attn_mfma(
    const unsigned short* __restrict__ qb, const unsigned short* __restrict__ kb,
    const unsigned short* __restrict__ vT, const float* __restrict__ btab,
    unsigned short* __restrict__ pob, float* __restrict__ pl, int klen)
{
    __shared__ float sbtw[2176 + 16];

    const int q0blk = blockIdx.x * 128;
    const int kt0   = blockIdx.z * klen;
    const int woff  = (S-1) + kt0 - q0blk - 127;

    int tid = threadIdx.x;
    for (int i = tid; i < klen + 128; i += 256) {
        int g = woff + i;
        sbtw[i] = btab[g < 0 ? 0 : (g > 4094 ? 4094 : g)];
    }
    __syncthreads();

    const int w  = tid >> 6, l = tid & 63;
    const int lr = l & 31,  hi = l >> 5;
    const int b  = blockIdx.y;
    const int q0 = q0blk + w * 32;

    const unsigned short* qrow = qb + ((size_t)(b*S) + q0 + lr) * DP + hi*8;
    bf16x8 qf0 = ldfrag(qrow);
    bf16x8 qf1 = ldfrag(qrow + 16);
    bf16x8 qf2 = ldfrag(qrow + 32);

    const unsigned short* kbase = kb + ((size_t)(b*S) + lr) * DP + hi*8;
    const unsigned short* vbase = vT + (size_t)lr*NROWS + (size_t)b*S + hi*8;

    f32x16 of0 = {0,0,0,0,0,0,0,0,0,0,0,0,0,0,0,0};
    f32x16 of1 = {0,0,0,0,0,0,0,0,0,0,0,0,0,0,0,0};
    float el = 0.f;

    const int bb = 127 - w*32 - lr + 4*hi;

    bf16x8 kfA[3], vfA[4], kfB[3], vfB[4];

    auto loadK = [&](int kt, bf16x8* kf) {
        const unsigned short* p = kbase + (size_t)kt*DP;
        kf[0] = ldfrag(p); kf[1] = ldfrag(p + 16); kf[2] = ldfrag(p + 32);
    };
    auto loadV = [&](int kt, bf16x8* vf) {
        const unsigned short* p = vbase + kt;
        vf[0] = ldfrag(p);
        vf[1] = ldfrag(p + 16);
        vf[2] = ldfrag(p + (size_t)32*NROWS);
        vf[3] = ldfrag(p + (size_t)32*NROWS + 16);
    };

    auto compute = [&](int ktl, const bf16x8* kf, const bf16x8* vf) {
        f32x16 c = {0,0,0,0,0,0,0,0,0,0,0,0,0,0,0,0};
        c = __builtin_amdgcn_mfma_f32_32x32x16_bf16(kf[0], qf0, c, 0,0,0);
        c = __builtin_amdgcn_mfma_f32_32x32x16_bf16(kf[1], qf1, c, 0,0,0);
        c = __builtin_amdgcn_mfma_f32_32x32x16_bf16(kf[2], qf2, c, 0,0,0);

        float e[16];
        #pragma unroll
        for (int r = 0; r < 16; ++r) {
            float s = c[r] + sbtw[bb + ktl + (r&3) + 8*(r>>2)];
            e[r] = __expf(s);
            el += e[r];
        }
        unsigned a0 = cvtpk(e[0],  e[1]);
        unsigned a1 = cvtpk(e[2],  e[3]);
        unsigned a2 = cvtpk(e[4],  e[5]);
        unsigned a3 = cvtpk(e[6],  e[7]);
        plswap(a0, a2);
        plswap(a1, a3);
        unsigned b0 = cvtpk(e[8],  e[9]);
        unsigned b1 = cvtpk(e[10], e[11]);
        unsigned b2 = cvtpk(e[12], e[13]);
        unsigned b3 = cvtpk(e[14], e[15]);
        plswap(b0, b2);
        plswap(b1, b3);
        uint4 u0 = {a0, a1, a2, a3};
        uint4 u1 = {b0, b1, b2, b3};
        bf16x8 pa0 = __builtin_bit_cast(bf16x8, u0);
        bf16x8 pa1 = __builtin_bit_cast(bf16x8, u1);

        of0 = __builtin_amdgcn_mfma_f32_32x32x16_bf16(pa0, vf[0], of0, 0,0,0);
        of0 = __builtin_amdgcn_mfma_f32_32x32x16_bf16(pa1, vf[1], of0, 0,0,0);
        of1 = __builtin_amdgcn_mfma_f32_32x32x16_bf16(pa0, vf[2], of1, 0,0,0);
        of1 = __builtin_amdgcn_mfma_f32_32x32x16_bf16(pa1, vf[3], of1, 0,0,0);
    };

    loadK(kt0, kfA); loadV(kt0, vfA);
    for (int kt = kt0; kt < kt0 + klen; kt += 64) {
        loadK(kt+32, kfB); loadV(kt+32, vfB);
        compute(kt - kt0, kfA, vfA);
        if (kt + 64 < kt0 + klen) { loadK(kt+64, kfA); loadV(kt+64, vfA); }
        compute(kt + 32 - kt0, kfB, vfB);
    }

    el += __shfl_xor(el, 32);

    const size_t rowbase = (size_t)blockIdx.z * NROWS + b*S + q0;
    #pragma unroll
    for (int r = 0; r < 16; ++r) {
        int qr = (r&3) + 8*(r>>2) + 4*hi;
        unsigned short* pr = pob + (rowbase + qr) * XSTR;
        pr[lr] = f2bf(of0[r]);
        if (lr < 8) pr[32 + lr] = f2bf(of1[r]);
    }
    if (hi == 0) pl[rowbase + lr] = el;
}

// ---------------- Kernel 4: combine + O-proj + residual + FF + rmsnorm, 2-wave col-split ----------------
__global__ __launch_bounds__(128) void k4_out_ff(
    const unsigned short* __restrict__ xb, const unsigned short* __restrict__ pob,
    const float* __restrict__ pl,
    const unsigned short* __restrict__ woT, const unsigned short* __restrict__ wiT,
    const unsigned short* __restrict__ wo2T, const float* __restrict__ lnf,
    float* __restrict__ out, int nsplit)
{
    __shared__ unsigned short sX[32][56];
    __shared__ float sSS[2][32];

    const int tid = threadIdx.x;
    const int w   = tid >> 6;
    const int l   = tid & 63;
    const int lr  = l & 31, hi = l >> 5;
    const int row = blockIdx.x * 32 + lr;
    const int cb  = w * 32;

    // combine split-K partials into full-d B-frags (duplicated per wave; L2-hot)
    float lsum = 0.f;
    for (int s = 0; s < nsplit; ++s) lsum += pl[(size_t)s*NROWS + row];
    const float linv = 1.0f / lsum;

    float a[3][8];
    #pragma unroll
    for (int t = 0; t < 3; ++t)
        #pragma unroll
        for (int j = 0; j < 8; ++j) a[t][j] = 0.f;
    for (int s = 0; s < nsplit; ++s) {
        const unsigned short* pr = pob + ((size_t)s*NROWS + row) * XSTR;
        #pragma unroll
        for (int t = 0; t < 3; ++t) {
            if (t == 2 && hi == 1) continue;          // d = 40..47 unused
            uint4 u = *(const uint4*)(pr + t*16 + hi*8);
            a[t][0] += bf2f((unsigned short)(u.x)); a[t][1] += bf2f((unsigned short)(u.x >> 16));
            a[t][2] += bf2f((unsigned short)(u.y)); a[t][3] += bf2f((unsigned short)(u.y >> 16));
            a[t][4] += bf2f((unsigned short)(u.z)); a[t][5] += bf2f((unsigned short)(u.z >> 16));
            a[t][6] += bf2f((unsigned short)(u.w)); a[t][7] += bf2f((unsigned short)(u.w >> 16));
        }
    }
    bf16x8 ab[3];
    #pragma unroll
    for (int t = 0; t < 3; ++t) {
        uint4 u = { cvtpk(a[t][0]*linv, a[t][1]*linv), cvtpk(a[t][2]*linv, a[t][3]*linv),
                    cvtpk(a[t][4]*linv, a[t][5]*linv), cvtpk(a[t][6]*linv, a[t][7]*linv) };
        ab[t] = __builtin_bit_cast(bf16x8, u);
    }

    // x2 tile = xres + a @ Wo (this wave's 32 cols)
    f32x16 c = {0,0,0,0,0,0,0,0,0,0,0,0,0,0,0,0};
    #pragma unroll
    for (int t = 0; t < 3; ++t)
        c = __builtin_amdgcn_mfma_f32_32x32x16_bf16(ldfrag(woT + (size_t)(cb+lr)*48 + t*16 + hi*8), ab[t], c, 0,0,0);

    const unsigned short* xr = xb + (size_t)row*XSTR;
    if (w == 0) {
        #pragma unroll
        for (int rr = 0; rr < 4; ++rr) {
            ushort4 v = *(const ushort4*)(xr + rr*8 + 4*hi);
            c[rr*4+0] += bf2f(v.x); c[rr*4+1] += bf2f(v.y);
            c[rr*4+2] += bf2f(v.z); c[rr*4+3] += bf2f(v.w);
        }
    } else {
        ushort4 v = *(const ushort4*)(xr + 32 + 4*hi);
        c[0] += bf2f(v.x); c[1] += bf2f(v.y); c[2] += bf2f(v.z); c[3] += bf2f(v.w);
        // cols 40..63: weights and xb are zero -> c stays 0
    }

    // rmsnorm(x2): cross-wave per-row reduce
    float ss = 0.f;
    #pragma unroll
    for (int r = 0; r < 16; ++r) ss += c[r]*c[r];
    ss += __shfl_xor(ss, 32);
    if (hi == 0) sSS[w][lr] = ss;
    __syncthreads();
    const float inv2 = rsqrtf((sSS[0][lr] + sSS[1][lr]) * (1.0f/D) + 1e-6f);

    f32x16 t0;
    #pragma unroll
    for (int r = 0; r < 16; ++r) t0[r] = c[r]*inv2;
    {
        uint4 u0, u1; repack1(t0, u0, u1);
        *(uint4*)(&sX[lr][cb + hi*8]) = u0;
        if (w == 0) *(uint4*)(&sX[lr][16 + hi*8]) = u1;
    }
    __syncthreads();
    bf16x8 hb[3];
    #pragma unroll
    for (int t = 0; t < 3; ++t) hb[t] = ldfrag(&sX[lr][t*16 + hi*8]);
    __syncthreads();   // reads done before sX rewrite

    // f = relu(h @ wi') tile
    f32x16 d = {0,0,0,0,0,0,0,0,0,0,0,0,0,0,0,0};
    #pragma unroll
    for (int t = 0; t < 3; ++t)
        d = __builtin_amdgcn_mfma_f32_32x32x16_bf16(ldfrag(wiT + (size_t)(cb+lr)*48 + t*16 + hi*8), hb[t], d, 0,0,0);
    #pragma unroll
    for (int r = 0; r < 16; ++r) d[r] = fmaxf(d[r], 0.f);
    {
        uint4 u0, u1; repack1(d, u0, u1);
        *(uint4*)(&sX[lr][cb + hi*8]) = u0;
        if (w == 0) *(uint4*)(&sX[lr][16 + hi*8]) = u1;
    }
    __syncthreads();
    bf16x8 fb[3];
    #pragma unroll
    for (int t = 0; t < 3; ++t) fb[t] = ldfrag(&sX[lr][t*16 + hi*8]);

    // x3 tile = x2 + f @ wo
    f32x16 e = {0,0,0,0,0,0,0,0,0,0,0,0,0,0,0,0};
    #pragma unroll
    for (int t = 0; t < 3; ++t)
        e = __builtin_amdgcn_mfma_f32_32x32x16_bf16(ldfrag(wo2T + (size_t)(cb+lr)*48 + t*16 + hi*8), fb[t], e, 0,0,0);
    #pragma unroll
    for (int r = 0; r < 16; ++r) e[r] += c[r];

    // final rmsnorm
    float ss2 = 0.f;
    #pragma unroll
    for (int r = 0; r < 16; ++r) ss2 += e[r]*e[r];
    ss2 += __shfl_xor(ss2, 32);
    if (hi == 0) sSS[w][lr] = ss2;
    __syncthreads();
    const float inv3 = rsqrtf((sSS[0][lr] + sSS[1][lr]) * (1.0f/D) + 1e-6f);

    float* orow = out + (size_t)row * D;
    if (w == 0) {
        #pragma unroll
        for (int rr = 0; rr < 4; ++rr) {
            float4 lf = *(const float4*)(lnf + rr*8 + 4*hi);
            float4 v = { e[rr*4+0]*inv3*lf.x, e[rr*4+1]*inv3*lf.y,
                         e[rr*4+2]*inv3*lf.z, e[rr*4+3]*inv3*lf.w };
            *(float4*)(orow + rr*8 + 4*hi) = v;
        }
    } else {
        float4 lf = *(const float4*)(lnf + 32 + 4*hi);
        float4 v = { e[0]*inv3*lf.x, e[1]*inv3*lf.y, e[2]*inv3*lf.z, e[3]*inv3*lf.w };
        *(float4*)(orow + 32 + 4*hi) = v;
    }
}

extern "C" void kernel_launch(void* const* d_in, const int* in_sizes, int n_in,
                              void* d_out, int out_size, void* d_ws, size_t ws_size,
                              hipStream_t stream) {
    const float* embs = (const float*)d_in[0];
    const float* Wa   = (const float*)d_in[1];
    const float* ba   = (const float*)d_in[2];
    const float* ln1  = (const float*)d_in[3];
    const float* Wq   = (const float*)d_in[4];
    const float* Wk   = (const float*)d_in[5];
    const float* Wv   = (const float*)d_in[6];
    const float* Wo   = (const float*)d_in[7];
    const float* ln2  = (const float*)d_in[8];
    const float* wi   = (const float*)d_in[9];
    const float* wo   = (const float*)d_in[10];
    const float* lnf  = (const float*)d_in[11];
    const float* rb   = (const float*)d_in[12];

    char* wsb = (char*)d_ws;
    unsigned short* xb   = (unsigned short*)(wsb);              // NROWS*48*2 = 1,572,864
    unsigned short* qb   = (unsigned short*)(wsb + 1572864);    // 2,097,152
    unsigned short* kbq  = (unsigned short*)(wsb + 3670016);    // 2,097,152
    unsigned short* vT   = (unsigned short*)(wsb + 5767168);    // 2,097,152
    unsigned short* waT  = (unsigned short*)(wsb + 7864320);    // 18,432
    unsigned short* wqT  = (unsigned short*)(wsb + 7882752);    // 6,144
    unsigned short* wkT  = (unsigned short*)(wsb + 7888896);
    unsigned short* wvT  = (unsigned short*)(wsb + 7895040);
    unsigned short* woT  = (unsigned short*)(wsb + 7901184);
    unsigned short* wiT  = (unsigned short*)(wsb + 7907328);
    unsigned short* wo2T = (unsigned short*)(wsb + 7913472);
    const size_t base = 7919616;

    int nsplit = 8;
    while (nsplit > 1 &&
           base + (size_t)nsplit*(1572864 + 65536) + 16384 > ws_size)
        nsplit >>= 1;
    unsigned short* pob = (unsigned short*)(wsb + base);                     // nsplit * NROWS*48*2
    float* pl   = (float*)(wsb + base + (size_t)nsplit*1572864);             // nsplit * NROWS*4
    float* btab = (float*)(wsb + base + (size_t)nsplit*(1572864 + 65536));   // 16,384
    int klen = S / nsplit;

    k0_prep<<<36, 256, 0, stream>>>(Wa, ba, ln1, Wq, Wk, Wv, Wo, ln2, wi, wo, rb,
                                    waT, wqT, wkT, wvT, woT, wiT, wo2T, btab);
    k1_adapter_qkv<<<NROWS/32, 128, 0, stream>>>(embs, waT, wqT, wkT, wvT, xb, qb, kbq, vT);
    k3_attn_mfma<<<dim3(S/128, B, nsplit), 256, 0, stream>>>(qb, kbq, vT, btab, pob, pl, klen);
    k4_out_ff<<<NROWS/32, 128, 0, stream>>>(xb, pob, pl, woT, wiT, wo2T, lnf, (float*)d_out, nsplit);
}